// Round 11
// baseline (501.938 us; speedup 1.0000x reference)
//
#include <hip/hip_runtime.h>
#include <cmath>

typedef _Float16 half8 __attribute__((ext_vector_type(8)));
typedef _Float16 half4v __attribute__((ext_vector_type(4)));
typedef __attribute__((ext_vector_type(4))) float floatx4;

#define GLOAD_LDS16(gp, lp)                                            \
  __builtin_amdgcn_global_load_lds(                                    \
      (const __attribute__((address_space(1))) void*)(gp),             \
      (__attribute__((address_space(3))) void*)(lp), 16, 0, 0)

static inline int cdiv(int a, int b) { return (a + b - 1) / b; }

// ------- merged prep: cast h0/W1/W2/W3 fp32->fp16, then centers cast + norms -------
__global__ void prep(const float* __restrict__ h0, const float* __restrict__ W1,
                     const float* __restrict__ W2, const float* __restrict__ W3,
                     const float* __restrict__ c1, const float* __restrict__ c2,
                     const float* __restrict__ c3,
                     _Float16* __restrict__ hh, _Float16* __restrict__ Wh1,
                     _Float16* __restrict__ Wh2, _Float16* __restrict__ Wh3,
                     _Float16* __restrict__ cb1, _Float16* __restrict__ cb2,
                     _Float16* __restrict__ cb3,
                     float* __restrict__ cn1, float* __restrict__ cn2,
                     float* __restrict__ cn3,
                     int nh, int nw, int castBlocks, int n1, int n2) {
  int t = threadIdx.x;
  if ((int)blockIdx.x < castBlocks) {
    int gi = (blockIdx.x * 256 + t) * 4;
    const float* src; _Float16* dst; int off;
    if (gi < nh)                { src = h0; dst = hh;  off = gi; }
    else if (gi < nh + nw)      { src = W1; dst = Wh1; off = gi - nh; }
    else if (gi < nh + 2 * nw)  { src = W2; dst = Wh2; off = gi - nh - nw; }
    else if (gi < nh + 3 * nw)  { src = W3; dst = Wh3; off = gi - nh - 2 * nw; }
    else return;
    float4 v = *(const float4*)(src + off);
    half4v o = {(_Float16)v.x, (_Float16)v.y, (_Float16)v.z, (_Float16)v.w};
    *(half4v*)(dst + off) = o;
    return;
  }
  int row = blockIdx.x - castBlocks;
  const float* c; _Float16* cb; float* cn;
  if (row < n1)            { c = c1; cb = cb1; cn = cn1; }
  else if (row < n1 + n2)  { row -= n1; c = c2; cb = cb2; cn = cn2; }
  else                     { row -= n1 + n2; c = c3; cb = cb3; cn = cn3; }
  float4 v = *(const float4*)(c + (size_t)row * 1024 + t * 4);
  half4v o = {(_Float16)v.x, (_Float16)v.y, (_Float16)v.z, (_Float16)v.w};
  *(half4v*)(cb + (size_t)row * 1024 + t * 4) = o;
  float s = v.x * v.x + v.y * v.y + v.z * v.z + v.w * v.w;
  #pragma unroll
  for (int off = 32; off > 0; off >>= 1) s += __shfl_down(s, off, 64);
  __shared__ float ws[4];
  if ((t & 63) == 0) ws[t >> 6] = s;
  __syncthreads();
  if (t == 0) cn[row] = ws[0] + ws[1] + ws[2] + ws[3];
}

// ------------- L1 softmax pass: finalize max from per-block pmax, exp in place, partial sums -------------
#define SM_CHUNK 64
__global__ void colexp_partial(_Float16* __restrict__ ST, const float* __restrict__ pmax,
                               float* __restrict__ psum, int mchunks, int ncur, int nprev) {
  int col = (blockIdx.x * 256 + threadIdx.x) * 4;
  if (col >= nprev) return;
  float m0 = -1e30f, m1 = -1e30f, m2 = -1e30f, m3 = -1e30f;
  for (int k = 0; k < mchunks; ++k) {
    float4 v = *(const float4*)(pmax + (size_t)k * nprev + col);
    m0 = fmaxf(m0, v.x); m1 = fmaxf(m1, v.y); m2 = fmaxf(m2, v.z); m3 = fmaxf(m3, v.w);
  }
  int j0 = blockIdx.y * SM_CHUNK;
  int j1 = min(j0 + SM_CHUNK, ncur);
  float s0 = 0.f, s1 = 0.f, s2 = 0.f, s3 = 0.f;
  for (int j = j0; j < j1; ++j) {
    size_t o = (size_t)j * nprev + col;
    half4v x = *(const half4v*)(ST + o);
    float e0 = __expf((float)x[0] - m0), e1 = __expf((float)x[1] - m1);
    float e2 = __expf((float)x[2] - m2), e3 = __expf((float)x[3] - m3);
    half4v e = {(_Float16)e0, (_Float16)e1, (_Float16)e2, (_Float16)e3};
    *(half4v*)(ST + o) = e;   // in place: same thread reads then writes same elem
    s0 += e0; s1 += e1; s2 += e2; s3 += e3;
  }
  float4 sv = {s0, s1, s2, s3};
  *(float4*)(psum + (size_t)blockIdx.y * nprev + col) = sv;
}

// ---------------- split-K reduce: out_fp16[i] = sum_s part[s][i] (fp16 partials) ----------------
__global__ void reduce_parts(const _Float16* __restrict__ part, _Float16* __restrict__ out,
                             int mn, int S) {
  int i = (blockIdx.x * 256 + threadIdx.x) * 4;
  if (i >= mn) return;
  float a0 = 0.f, a1 = 0.f, a2 = 0.f, a3 = 0.f;
  for (int s = 0; s < S; ++s) {
    half4v v = *(const half4v*)(part + (size_t)s * mn + i);
    a0 += (float)v[0]; a1 += (float)v[1]; a2 += (float)v[2]; a3 += (float)v[3];
  }
  half4v o = {(_Float16)a0, (_Float16)a1, (_Float16)a2, (_Float16)a3};
  *(half4v*)(out + i) = o;
}

// ---------------- NT fp16 MFMA GEMM: C[M][N] = A[M][K] * B[N][K]^T ----------------
// global_load_lds (16B) staging, XOR-swizzled LDS (0 bank conflicts, verified r4).
// __launch_bounds__(256,4): (256,5) spilled (r9: VGPR 64->48, +340MB scratch writes,
// MfmaUtil 31->14%). Do NOT tighten below the observed 64-VGPR working set.
enum { EP_LOGIT = 0, EP_TANH = 1, EP_TANHP = 2, EP_F16 = 3, EP_F32 = 4, EP_PART = 5 };

template<int BM, int BN, int EPI>
__launch_bounds__(256, 4)
__global__ void gemm_nt(const _Float16* __restrict__ A,
                        const _Float16* __restrict__ B,
                        void* __restrict__ Cout,
                        const float* __restrict__ aux1,   // cn[M] or bias[M]
                        const float* __restrict__ aux2,   // psum (EP_TANH)
                        float* __restrict__ pmax,         // EP_LOGIT out
                        int pnchunks,                     // EP_TANH psum chunk count
                        int M, int N, int K, int kLen) {
  constexpr int BK = 64;                 // 128 B/row, unpadded (global_load_lds needs it)
  constexpr int WTM = BM / 2, WTN = BN / 2;
  constexpr int FM = WTM / 16, FN = WTN / 16;
  __shared__ __align__(16) _Float16 As[BM * BK];
  __shared__ __align__(16) _Float16 Bs[BN * BK];
  float* smf = (float*)As;               // aliased: used only after the K-loop
  const int tid  = threadIdx.x;
  const int lane = tid & 63;
  const int wave = tid >> 6;
  const int wm = wave >> 1, wn = wave & 1;
  const int mBase = blockIdx.x * BM, nBase = blockIdx.y * BN;
  const int kBase = blockIdx.z * kLen;
  const int lr    = lane & 15;           // fragment row (A: m, B: n)
  const int kHalf = (lane >> 4) << 3;    // fragment k offset: 0,8,16,24

  const int srOff  = lane >> 3;                        // row within 8-row staging group
  const int schunk = (lane & 7) ^ srOff;               // swizzled global K-chunk
  floatx4 acc[FM][FN] = {};
  constexpr int AV = BM * BK / (256 * 8);
  constexpr int BV = BN * BK / (256 * 8);

  for (int k0 = kBase; k0 < kBase + kLen; k0 += BK) {  // kLen % 64 == 0 everywhere
    #pragma unroll
    for (int v = 0; v < AV; ++v) {
      int rowBase = v * 32 + wave * 8;
      int gm = mBase + rowBase + srOff;
      if (gm >= M) gm = M - 1;                         // clamp: feeds only discarded rows
      GLOAD_LDS16(A + (size_t)gm * K + k0 + schunk * 8, &As[rowBase * BK]);
    }
    #pragma unroll
    for (int v = 0; v < BV; ++v) {
      int rowBase = v * 32 + wave * 8;
      int gn = nBase + rowBase + srOff;
      if (gn >= N) gn = N - 1;
      GLOAD_LDS16(B + (size_t)gn * K + k0 + schunk * 8, &Bs[rowBase * BK]);
    }
    __syncthreads();
    #pragma unroll
    for (int kk = 0; kk < BK; kk += 32) {
      const int q = (kk + kHalf) >> 3;
      half8 af[FM], bfv[FN];
      #pragma unroll
      for (int i = 0; i < FM; ++i) {
        int r = wm * WTM + i * 16 + lr;
        af[i] = *(const half8*)(&As[r * BK + ((q ^ (r & 7)) << 3)]);
      }
      #pragma unroll
      for (int j = 0; j < FN; ++j) {
        int r = wn * WTN + j * 16 + lr;
        bfv[j] = *(const half8*)(&Bs[r * BK + ((q ^ (r & 7)) << 3)]);
      }
      #pragma unroll
      for (int i = 0; i < FM; ++i)
        #pragma unroll
        for (int j = 0; j < FN; ++j)
          acc[i][j] = __builtin_amdgcn_mfma_f32_16x16x32_f16(af[i], bfv[j], acc[i][j], 0, 0, 0);
    }
    __syncthreads();
  }
  // here: all waves past the final barrier; staging LDS is dead -> smf may alias it

  if (EPI == EP_TANH) {                  // linv[col] = 1 / sum_k psum[k][col]
    if (tid < BN) {
      int col = nBase + tid;
      float ssum = 0.f;
      if (col < N)
        for (int k = 0; k < pnchunks; ++k) ssum += aux2[(size_t)k * N + col];
      smf[tid] = 1.f / ssum;
    }
    __syncthreads();
  }

  // epilogue: D row=(lane>>4)*4+r, col=lane&15 (m89-verified mapping)
  const int rBase = (lane >> 4) << 2;
  float lmax[FN];
  #pragma unroll
  for (int j = 0; j < FN; ++j) lmax[j] = -1e30f;
  #pragma unroll
  for (int i = 0; i < FM; ++i) {
    #pragma unroll
    for (int j = 0; j < FN; ++j) {
      #pragma unroll
      for (int r = 0; r < 4; ++r) {
        int row = mBase + wm * WTM + i * 16 + rBase + r;
        int col = nBase + wn * WTN + j * 16 + lr;
        if (row < M && col < N) {
          float v = acc[i][j][r];
          size_t o = (size_t)row * N + col;
          if (EPI == EP_LOGIT) {
            v = 0.5f * v - 0.25f * aux1[row];
            ((_Float16*)Cout)[o] = (_Float16)v;
            lmax[j] = fmaxf(lmax[j], v);
          } else if (EPI == EP_TANH) {
            v = tanhf(v + aux1[row]) * smf[col - nBase];
            ((_Float16*)Cout)[o] = (_Float16)v;
          } else if (EPI == EP_TANHP) {
            v = tanhf(v + aux1[row]);
            ((_Float16*)Cout)[o] = (_Float16)v;
          } else if (EPI == EP_F16) {
            ((_Float16*)Cout)[o] = (_Float16)v;
          } else if (EPI == EP_PART) {
            ((_Float16*)Cout)[(size_t)blockIdx.z * M * N + o] = (_Float16)v;
          } else {
            ((float*)Cout)[o] = v;
          }
        }
      }
    }
  }
  if (EPI == EP_LOGIT) {
    #pragma unroll
    for (int j = 0; j < FN; ++j) {
      float m = lmax[j];
      m = fmaxf(m, __shfl_xor(m, 16, 64));
      m = fmaxf(m, __shfl_xor(m, 32, 64));
      if ((lane >> 4) == 0) smf[wm * BN + wn * WTN + j * 16 + lr] = m;
    }
    __syncthreads();
    if (tid < BN) {
      int col = nBase + tid;
      if (col < N)
        pmax[(size_t)blockIdx.x * N + col] = fmaxf(smf[tid], smf[BN + tid]);
    }
  }
}

// ------------- fused logit + full column softmax (ncur fits in one block: BM == M) -------------
// Writes E'[j][col] = exp(logit - m_col) / l_col  (1/l folded in — no linv downstream).
template<int BM, int BN>
__launch_bounds__(256, 2)
__global__ void fused_ls(const _Float16* __restrict__ A,   // centers [M x K]
                         const _Float16* __restrict__ B,   // h_prev  [N x K]
                         _Float16* __restrict__ Eout,      // [M x N]
                         const float* __restrict__ cn,
                         int M, int N, int K) {
  constexpr int BK = 64;
  constexpr int WTM = BM / 2, WTN = BN / 2;
  constexpr int FM = WTM / 16, FN = WTN / 16;
  constexpr int TLD = BN + 4;                       // padded tile LD (bank stagger)
  constexpr int STAGE_B = (BM + BN) * BK * 2;
  constexpr int TILE_B  = BM * TLD * 4;
  constexpr int SM_B = STAGE_B > TILE_B ? STAGE_B : TILE_B;
  __shared__ __align__(16) char smem[SM_B];
  _Float16* As = (_Float16*)smem;
  _Float16* Bs = As + BM * BK;
  float* tile = (float*)smem;                       // reused after K-loop
  __shared__ float redm[256], reds[256];
  const int tid  = threadIdx.x;
  const int lane = tid & 63;
  const int wave = tid >> 6;
  const int wm = wave >> 1, wn = wave & 1;
  const int nBase = blockIdx.x * BN;
  const int lr    = lane & 15;
  const int kHalf = (lane >> 4) << 3;
  const int srOff  = lane >> 3;
  const int schunk = (lane & 7) ^ srOff;
  floatx4 acc[FM][FN] = {};
  constexpr int AV = BM * BK / (256 * 8);
  constexpr int BV = BN * BK / (256 * 8);

  for (int k0 = 0; k0 < K; k0 += BK) {
    #pragma unroll
    for (int v = 0; v < AV; ++v) {
      int rowBase = v * 32 + wave * 8;
      GLOAD_LDS16(A + (size_t)(rowBase + srOff) * K + k0 + schunk * 8, &As[rowBase * BK]);
    }
    #pragma unroll
    for (int v = 0; v < BV; ++v) {
      int rowBase = v * 32 + wave * 8;
      GLOAD_LDS16(B + (size_t)(nBase + rowBase + srOff) * K + k0 + schunk * 8, &Bs[rowBase * BK]);
    }
    __syncthreads();
    #pragma unroll
    for (int kk = 0; kk < BK; kk += 32) {
      const int q = (kk + kHalf) >> 3;
      half8 af[FM], bfv[FN];
      #pragma unroll
      for (int i = 0; i < FM; ++i) {
        int r = wm * WTM + i * 16 + lr;
        af[i] = *(const half8*)(&As[r * BK + ((q ^ (r & 7)) << 3)]);
      }
      #pragma unroll
      for (int j = 0; j < FN; ++j) {
        int r = wn * WTN + j * 16 + lr;
        bfv[j] = *(const half8*)(&Bs[r * BK + ((q ^ (r & 7)) << 3)]);
      }
      #pragma unroll
      for (int i = 0; i < FM; ++i)
        #pragma unroll
        for (int j = 0; j < FN; ++j)
          acc[i][j] = __builtin_amdgcn_mfma_f32_16x16x32_f16(af[i], bfv[j], acc[i][j], 0, 0, 0);
    }
    __syncthreads();                                // also protects staging->tile reuse
  }

  // logits -> fp32 LDS tile
  const int rBase = (lane >> 4) << 2;
  #pragma unroll
  for (int i = 0; i < FM; ++i)
    #pragma unroll
    for (int j = 0; j < FN; ++j)
      #pragma unroll
      for (int r = 0; r < 4; ++r) {
        int row = wm * WTM + i * 16 + rBase + r;    // row < BM == M
        int col = wn * WTN + j * 16 + lr;
        tile[row * TLD + col] = 0.5f * acc[i][j][r] - 0.25f * cn[row];
      }
  __syncthreads();

  // per-column softmax: P threads per column, rows strided
  constexpr int P = 256 / BN;
  const int c = tid & (BN - 1);
  const int p = tid / BN;
  float m = -1e30f;
  for (int j = p; j < M; j += P) m = fmaxf(m, tile[j * TLD + c]);
  redm[p * BN + c] = m;
  __syncthreads();
  float mf = redm[c];
  #pragma unroll
  for (int q = 1; q < P; ++q) mf = fmaxf(mf, redm[q * BN + c]);
  float s = 0.f;
  for (int j = p; j < M; j += P) {
    float e = __expf(tile[j * TLD + c] - mf);
    tile[j * TLD + c] = e;                          // own cells only
    s += e;
  }
  reds[p * BN + c] = s;
  __syncthreads();
  float l = 0.f;
  #pragma unroll
  for (int q = 0; q < P; ++q) l += reds[q * BN + c];
  const float li = 1.f / l;
  for (int j = p; j < M; j += P)
    Eout[(size_t)j * N + nBase + c] = (_Float16)(tile[j * TLD + c] * li);
}

// ------------- level 3 tail: t3-slice GEMM + tanh, then out = E3 * t3^T, one kernel -------------
// Block bx owns output n-slice [64*bx, 64*bx+64). Stage 1: T[64][256] =
// tanh(W3[n0+.]·h2^T + b3). Stage 2: out[32][64] = E3'(32x256) · T^T (K=256).
__launch_bounds__(256)
__global__ void level3_out(const _Float16* __restrict__ W3h,   // [1024 x 1024]
                           const _Float16* __restrict__ h2,    // [256 x 1024]
                           const _Float16* __restrict__ E3,    // [32 x 256], 1/l folded
                           const float* __restrict__ b3,
                           float* __restrict__ out) {          // [32 x 1024]
  constexpr int BK = 64, K = 1024, NI = 256, MO = 32, NS = 64;
  constexpr int T3LD = NI + 8;                         // 264 (16B-aligned rows: 264%8==0)
  __shared__ __align__(16) _Float16 smem[(NS + NI) * BK];  // 40 KB staging
  _Float16* As = smem;                                 // W3 slice 64xBK
  _Float16* Bs = smem + NS * BK;                       // h2 256xBK
  _Float16* t3 = smem;                                 // aliased after stage 1 (33.8 KB)
  const int tid  = threadIdx.x;
  const int lane = tid & 63;
  const int wave = tid >> 6;
  const int wm = wave >> 1, wn = wave & 1;             // stage-1 tiling: 2x2 waves
  const int n0 = blockIdx.x * NS;
  const int lr    = lane & 15;
  const int kHalf = (lane >> 4) << 3;
  const int srOff  = lane >> 3;
  const int schunk = (lane & 7) ^ srOff;
  const int rBase = (lane >> 4) << 2;

  // ---- stage 1: C1[64][256] = W3slice · h2^T, K=1024 ----
  floatx4 acc[2][8] = {};                              // WTM=32 (FM=2), WTN=128 (FN=8)
  for (int k0 = 0; k0 < K; k0 += BK) {
    #pragma unroll
    for (int v = 0; v < 2; ++v) {                      // A: 64 rows
      int rowBase = v * 32 + wave * 8;
      GLOAD_LDS16(W3h + (size_t)(n0 + rowBase + srOff) * K + k0 + schunk * 8, &As[rowBase * BK]);
    }
    #pragma unroll
    for (int v = 0; v < 8; ++v) {                      // B: 256 rows
      int rowBase = v * 32 + wave * 8;
      GLOAD_LDS16(h2 + (size_t)(rowBase + srOff) * K + k0 + schunk * 8, &Bs[rowBase * BK]);
    }
    __syncthreads();
    #pragma unroll
    for (int kk = 0; kk < BK; kk += 32) {
      const int q = (kk + kHalf) >> 3;
      half8 af[2], bfv[8];
      #pragma unroll
      for (int i = 0; i < 2; ++i) {
        int r = wm * 32 + i * 16 + lr;
        af[i] = *(const half8*)(&As[r * BK + ((q ^ (r & 7)) << 3)]);
      }
      #pragma unroll
      for (int j = 0; j < 8; ++j) {
        int r = wn * 128 + j * 16 + lr;
        bfv[j] = *(const half8*)(&Bs[r * BK + ((q ^ (r & 7)) << 3)]);
      }
      #pragma unroll
      for (int i = 0; i < 2; ++i)
        #pragma unroll
        for (int j = 0; j < 8; ++j)
          acc[i][j] = __builtin_amdgcn_mfma_f32_16x16x32_f16(af[i], bfv[j], acc[i][j], 0, 0, 0);
    }
    __syncthreads();
  }
  // staging dead; write tanh(C1 + b3) into t3[n][i] (aliases staging)
  #pragma unroll
  for (int i = 0; i < 2; ++i)
    #pragma unroll
    for (int j = 0; j < 8; ++j)
      #pragma unroll
      for (int r = 0; r < 4; ++r) {
        int n = wm * 32 + i * 16 + rBase + r;          // [0,64)
        int ii = wn * 128 + j * 16 + lr;               // [0,256)
        t3[n * T3LD + ii] = (_Float16)tanhf(acc[i][j][r] + b3[n0 + n]);
      }
  __syncthreads();

  // ---- stage 2: out[32][64] = E3(32x256) · t3^T, K=256 ----
  // per-wave: 16-col slice (wave), rows 0..32 (FM=2)
  floatx4 acc2[2] = {};
  for (int k0 = 0; k0 < NI; k0 += 32) {
    half8 af[2];
    #pragma unroll
    for (int i = 0; i < 2; ++i)
      af[i] = *(const half8*)(E3 + (size_t)(i * 16 + lr) * NI + k0 + kHalf);
    half8 bf = *(const half8*)(&t3[(wave * 16 + lr) * T3LD + k0 + kHalf]);
    #pragma unroll
    for (int i = 0; i < 2; ++i)
      acc2[i] = __builtin_amdgcn_mfma_f32_16x16x32_f16(af[i], bf, acc2[i], 0, 0, 0);
  }
  #pragma unroll
  for (int i = 0; i < 2; ++i)
    #pragma unroll
    for (int r = 0; r < 4; ++r) {
      int j = i * 16 + rBase + r;                      // [0,32)
      int n = n0 + wave * 16 + lr;
      out[(size_t)j * 1024 + n] = acc2[i][r];
    }
}

// returns the BM actually used (host needs it for pmax chunk count)
template<int EPI>
static int launch_gemm(int M, int N, int K, const _Float16* A, const _Float16* B,
                       void* C, const float* a1, const float* a2, float* pmax,
                       int pnchunks, hipStream_t s) {
  long b128   = (long)cdiv(M, 128) * cdiv(N, 128);
  long b12864 = (long)cdiv(M, 128) * cdiv(N, 64);
  if (b128 >= 192) {
    gemm_nt<128, 128, EPI><<<dim3(cdiv(M, 128), cdiv(N, 128)), 256, 0, s>>>(
        A, B, C, a1, a2, pmax, pnchunks, M, N, K, K);
    return 128;
  } else if (M >= 128 && b12864 >= 192) {
    gemm_nt<128, 64, EPI><<<dim3(cdiv(M, 128), cdiv(N, 64)), 256, 0, s>>>(
        A, B, C, a1, a2, pmax, pnchunks, M, N, K, K);
    return 128;
  } else {
    gemm_nt<64, 64, EPI><<<dim3(cdiv(M, 64), cdiv(N, 64)), 256, 0, s>>>(
        A, B, C, a1, a2, pmax, pnchunks, M, N, K, K);
    return 64;
  }
}

static void launch_gemm_splitk(int M, int N, int K, int S,
                               const _Float16* A, const _Float16* B,
                               _Float16* Cpart, _Float16* Cout, hipStream_t s) {
  int kLen = K / S;
  long b128 = (long)cdiv(M, 128) * cdiv(N, 128) * S;
  if (M >= 128 && N >= 128 && b128 >= 256) {
    gemm_nt<128, 128, EP_PART><<<dim3(cdiv(M, 128), cdiv(N, 128), S), 256, 0, s>>>(
        A, B, Cpart, nullptr, nullptr, nullptr, 0, M, N, K, kLen);
  } else {
    gemm_nt<64, 64, EP_PART><<<dim3(cdiv(M, 64), cdiv(N, 64), S), 256, 0, s>>>(
        A, B, Cpart, nullptr, nullptr, nullptr, 0, M, N, K, kLen);
  }
  int mn = M * N;
  reduce_parts<<<cdiv(mn, 1024), 256, 0, s>>>(Cpart, Cout, mn, S);
}

extern "C" void kernel_launch(void* const* d_in, const int* in_sizes, int n_in,
                              void* d_out, int out_size, void* d_ws, size_t ws_size,
                              hipStream_t stream) {
  const float* h0 = (const float*)d_in[0];
  const float* c1 = (const float*)d_in[1];
  const float* c2 = (const float*)d_in[2];
  const float* c3 = (const float*)d_in[3];
  const float* W1 = (const float*)d_in[4];
  const float* b1 = (const float*)d_in[5];
  const float* W2 = (const float*)d_in[6];
  const float* b2 = (const float*)d_in[7];
  const float* W3 = (const float*)d_in[8];
  const float* b3 = (const float*)d_in[9];

  const int d = 1024;
  const int N0 = 16384, N1 = 2048, N2 = 256, N3 = 32;

  char* w = (char*)d_ws;
  size_t off = 0;
  auto alloc = [&](size_t bytes) {
    void* p = w + off;
    off += (bytes + 255) & ~(size_t)255;
    return p;
  };
  _Float16* hb  = (_Float16*)alloc((size_t)N0 * d * 2);   // 32 MB
  _Float16* cb1 = (_Float16*)alloc((size_t)N1 * d * 2);
  _Float16* cb2 = (_Float16*)alloc((size_t)N2 * d * 2);
  _Float16* cb3 = (_Float16*)alloc((size_t)N3 * d * 2);
  float* cn1 = (float*)alloc((size_t)N1 * 4);
  float* cn2 = (float*)alloc((size_t)N2 * 4);
  float* cn3 = (float*)alloc((size_t)N3 * 4);
  _Float16* Wb1 = (_Float16*)alloc((size_t)d * d * 2);
  _Float16* Wb2 = (_Float16*)alloc((size_t)d * d * 2);
  _Float16* Wb3 = (_Float16*)alloc((size_t)d * d * 2);
  _Float16* ST = (_Float16*)alloc((size_t)N1 * N0 * 2);   // 64 MB, E overwrites in place
  _Float16* tT = (_Float16*)alloc((size_t)d * N0 * 2);    // 32 MB
  float* pmax = (float*)alloc((size_t)32 * N0 * 4);       // per-block column maxes (L1)
  float* psum = (float*)alloc((size_t)32 * N0 * 4);       // per-chunk column sums (L1)
  _Float16* h1b = (_Float16*)alloc((size_t)N1 * d * 2);
  _Float16* h2b = (_Float16*)alloc((size_t)N2 * d * 2);
  _Float16* Cpart = (_Float16*)alloc((size_t)8 * N1 * d * 2);  // 32 MB fp16 split-K partials
  _Float16* E = ST;
  (void)ws_size; (void)in_sizes; (void)n_in; (void)out_size;

  // ---- prep: one kernel (casts + center norms) ----
  int nh = N0 * d, nw = d * d;
  int castBlocks = cdiv(nh + 3 * nw, 1024);
  prep<<<castBlocks + N1 + N2 + N3, 256, 0, stream>>>(
      h0, W1, W2, W3, c1, c2, c3, hb, Wb1, Wb2, Wb3, cb1, cb2, cb3,
      cn1, cn2, cn3, nh, nw, castBlocks, N1, N2);

  // ---- level 1: h[16384] -> h1[2048] (2-pass softmax; ncur too big for in-block) ----
  int bm = launch_gemm<EP_LOGIT>(N1, N0, d, cb1, hb, ST, cn1, nullptr, pmax, 0, stream);
  colexp_partial<<<dim3(N0 / 1024, cdiv(N1, SM_CHUNK)), 256, 0, stream>>>(
      ST, pmax, psum, cdiv(N1, bm), N1, N0);
  launch_gemm<EP_TANH>(d, N0, d, Wb1, hb, tT, b1, psum, nullptr, cdiv(N1, SM_CHUNK), stream);
  launch_gemm_splitk(N1, d, N0, 8, E, tT, Cpart, h1b, stream);   // 16x8x8 = 1024 blocks

  // ---- level 2: h1[2048] -> h2[256] (in-block softmax, 1/l folded into E') ----
  fused_ls<256, 32><<<N1 / 32, 256, 0, stream>>>(cb2, h1b, E, cn2, N2, N1, d);
  launch_gemm<EP_TANHP>(d, N1, d, Wb2, h1b, tT, b2, nullptr, nullptr, 0, stream);
  launch_gemm_splitk(N2, d, N1, 8, E, tT, Cpart, h2b, stream);   // 64x64: 4x16x8 = 512 blocks

  // ---- level 3: h2[256] -> out[32][1024] fp32 (2 kernels) ----
  fused_ls<32, 64><<<N2 / 64, 256, 0, stream>>>(cb3, h2b, E, cn3, N3, N2, d);
  level3_out<<<16, 256, 0, stream>>>(Wb3, h2b, E, b3, (float*)d_out);
}

// Round 12
// 490.648 us; speedup vs baseline: 1.0230x; 1.0230x over previous
//
#include <hip/hip_runtime.h>
#include <cmath>

typedef _Float16 half8 __attribute__((ext_vector_type(8)));
typedef _Float16 half4v __attribute__((ext_vector_type(4)));
typedef __attribute__((ext_vector_type(4))) float floatx4;

#define GLOAD_LDS16(gp, lp)                                            \
  __builtin_amdgcn_global_load_lds(                                    \
      (const __attribute__((address_space(1))) void*)(gp),             \
      (__attribute__((address_space(3))) void*)(lp), 16, 0, 0)

static inline int cdiv(int a, int b) { return (a + b - 1) / b; }

// ------- merged prep: cast h0/W1/W2/W3 fp32->fp16, then centers cast + norms -------
__global__ void prep(const float* __restrict__ h0, const float* __restrict__ W1,
                     const float* __restrict__ W2, const float* __restrict__ W3,
                     const float* __restrict__ c1, const float* __restrict__ c2,
                     const float* __restrict__ c3,
                     _Float16* __restrict__ hh, _Float16* __restrict__ Wh1,
                     _Float16* __restrict__ Wh2, _Float16* __restrict__ Wh3,
                     _Float16* __restrict__ cb1, _Float16* __restrict__ cb2,
                     _Float16* __restrict__ cb3,
                     float* __restrict__ cn1, float* __restrict__ cn2,
                     float* __restrict__ cn3,
                     int nh, int nw, int castBlocks, int n1, int n2) {
  int t = threadIdx.x;
  if ((int)blockIdx.x < castBlocks) {
    int gi = (blockIdx.x * 256 + t) * 4;
    const float* src; _Float16* dst; int off;
    if (gi < nh)                { src = h0; dst = hh;  off = gi; }
    else if (gi < nh + nw)      { src = W1; dst = Wh1; off = gi - nh; }
    else if (gi < nh + 2 * nw)  { src = W2; dst = Wh2; off = gi - nh - nw; }
    else if (gi < nh + 3 * nw)  { src = W3; dst = Wh3; off = gi - nh - 2 * nw; }
    else return;
    float4 v = *(const float4*)(src + off);
    half4v o = {(_Float16)v.x, (_Float16)v.y, (_Float16)v.z, (_Float16)v.w};
    *(half4v*)(dst + off) = o;
    return;
  }
  int row = blockIdx.x - castBlocks;
  const float* c; _Float16* cb; float* cn;
  if (row < n1)            { c = c1; cb = cb1; cn = cn1; }
  else if (row < n1 + n2)  { row -= n1; c = c2; cb = cb2; cn = cn2; }
  else                     { row -= n1 + n2; c = c3; cb = cb3; cn = cn3; }
  float4 v = *(const float4*)(c + (size_t)row * 1024 + t * 4);
  half4v o = {(_Float16)v.x, (_Float16)v.y, (_Float16)v.z, (_Float16)v.w};
  *(half4v*)(cb + (size_t)row * 1024 + t * 4) = o;
  float s = v.x * v.x + v.y * v.y + v.z * v.z + v.w * v.w;
  #pragma unroll
  for (int off = 32; off > 0; off >>= 1) s += __shfl_down(s, off, 64);
  __shared__ float ws[4];
  if ((t & 63) == 0) ws[t >> 6] = s;
  __syncthreads();
  if (t == 0) cn[row] = ws[0] + ws[1] + ws[2] + ws[3];
}

// ------------- L1 softmax pass: finalize max from per-block pmax, exp in place, partial sums -------------
#define SM_CHUNK 64
__global__ void colexp_partial(_Float16* __restrict__ ST, const float* __restrict__ pmax,
                               float* __restrict__ psum, int mchunks, int ncur, int nprev) {
  int col = (blockIdx.x * 256 + threadIdx.x) * 4;
  if (col >= nprev) return;
  float m0 = -1e30f, m1 = -1e30f, m2 = -1e30f, m3 = -1e30f;
  for (int k = 0; k < mchunks; ++k) {
    float4 v = *(const float4*)(pmax + (size_t)k * nprev + col);
    m0 = fmaxf(m0, v.x); m1 = fmaxf(m1, v.y); m2 = fmaxf(m2, v.z); m3 = fmaxf(m3, v.w);
  }
  int j0 = blockIdx.y * SM_CHUNK;
  int j1 = min(j0 + SM_CHUNK, ncur);
  float s0 = 0.f, s1 = 0.f, s2 = 0.f, s3 = 0.f;
  for (int j = j0; j < j1; ++j) {
    size_t o = (size_t)j * nprev + col;
    half4v x = *(const half4v*)(ST + o);
    float e0 = __expf((float)x[0] - m0), e1 = __expf((float)x[1] - m1);
    float e2 = __expf((float)x[2] - m2), e3 = __expf((float)x[3] - m3);
    half4v e = {(_Float16)e0, (_Float16)e1, (_Float16)e2, (_Float16)e3};
    *(half4v*)(ST + o) = e;   // in place: same thread reads then writes same elem
    s0 += e0; s1 += e1; s2 += e2; s3 += e3;
  }
  float4 sv = {s0, s1, s2, s3};
  *(float4*)(psum + (size_t)blockIdx.y * nprev + col) = sv;
}

// ---------------- split-K reduce: out_fp16[i] = sum_s part[s][i] (fp16 partials) ----------------
__global__ void reduce_parts(const _Float16* __restrict__ part, _Float16* __restrict__ out,
                             int mn, int S) {
  int i = (blockIdx.x * 256 + threadIdx.x) * 4;
  if (i >= mn) return;
  float a0 = 0.f, a1 = 0.f, a2 = 0.f, a3 = 0.f;
  for (int s = 0; s < S; ++s) {
    half4v v = *(const half4v*)(part + (size_t)s * mn + i);
    a0 += (float)v[0]; a1 += (float)v[1]; a2 += (float)v[2]; a3 += (float)v[3];
  }
  half4v o = {(_Float16)a0, (_Float16)a1, (_Float16)a2, (_Float16)a3};
  *(half4v*)(out + i) = o;
}

// ---------------- NT fp16 MFMA GEMM: C[M][N] = A[M][K] * B[N][K]^T ----------------
// global_load_lds (16B) staging, XOR-swizzled LDS (0 bank conflicts, verified r4).
// __launch_bounds__(256,4): (256,5) spilled (r9: VGPR 64->48, +340MB scratch writes,
// MfmaUtil 31->14%). Do NOT tighten below the observed 64-VGPR working set.
enum { EP_LOGIT = 0, EP_TANH = 1, EP_TANHP = 2, EP_F16 = 3, EP_F32 = 4, EP_PART = 5 };

template<int BM, int BN, int EPI>
__launch_bounds__(256, 4)
__global__ void gemm_nt(const _Float16* __restrict__ A,
                        const _Float16* __restrict__ B,
                        void* __restrict__ Cout,
                        const float* __restrict__ aux1,   // cn[M] or bias[M]
                        const float* __restrict__ aux2,   // psum (EP_TANH)
                        float* __restrict__ pmax,         // EP_LOGIT out
                        int pnchunks,                     // EP_TANH psum chunk count
                        int M, int N, int K, int kLen) {
  constexpr int BK = 64;                 // 128 B/row, unpadded (global_load_lds needs it)
  constexpr int WTM = BM / 2, WTN = BN / 2;
  constexpr int FM = WTM / 16, FN = WTN / 16;
  __shared__ __align__(16) _Float16 As[BM * BK];
  __shared__ __align__(16) _Float16 Bs[BN * BK];
  float* smf = (float*)As;               // aliased: used only after the K-loop
  const int tid  = threadIdx.x;
  const int lane = tid & 63;
  const int wave = tid >> 6;
  const int wm = wave >> 1, wn = wave & 1;
  const int mBase = blockIdx.x * BM, nBase = blockIdx.y * BN;
  const int kBase = blockIdx.z * kLen;
  const int lr    = lane & 15;           // fragment row (A: m, B: n)
  const int kHalf = (lane >> 4) << 3;    // fragment k offset: 0,8,16,24

  const int srOff  = lane >> 3;                        // row within 8-row staging group
  const int schunk = (lane & 7) ^ srOff;               // swizzled global K-chunk
  floatx4 acc[FM][FN] = {};
  constexpr int AV = BM * BK / (256 * 8);
  constexpr int BV = BN * BK / (256 * 8);

  for (int k0 = kBase; k0 < kBase + kLen; k0 += BK) {  // kLen % 64 == 0 everywhere
    #pragma unroll
    for (int v = 0; v < AV; ++v) {
      int rowBase = v * 32 + wave * 8;
      int gm = mBase + rowBase + srOff;
      if (gm >= M) gm = M - 1;                         // clamp: feeds only discarded rows
      GLOAD_LDS16(A + (size_t)gm * K + k0 + schunk * 8, &As[rowBase * BK]);
    }
    #pragma unroll
    for (int v = 0; v < BV; ++v) {
      int rowBase = v * 32 + wave * 8;
      int gn = nBase + rowBase + srOff;
      if (gn >= N) gn = N - 1;
      GLOAD_LDS16(B + (size_t)gn * K + k0 + schunk * 8, &Bs[rowBase * BK]);
    }
    __syncthreads();
    #pragma unroll
    for (int kk = 0; kk < BK; kk += 32) {
      const int q = (kk + kHalf) >> 3;
      half8 af[FM], bfv[FN];
      #pragma unroll
      for (int i = 0; i < FM; ++i) {
        int r = wm * WTM + i * 16 + lr;
        af[i] = *(const half8*)(&As[r * BK + ((q ^ (r & 7)) << 3)]);
      }
      #pragma unroll
      for (int j = 0; j < FN; ++j) {
        int r = wn * WTN + j * 16 + lr;
        bfv[j] = *(const half8*)(&Bs[r * BK + ((q ^ (r & 7)) << 3)]);
      }
      #pragma unroll
      for (int i = 0; i < FM; ++i)
        #pragma unroll
        for (int j = 0; j < FN; ++j)
          acc[i][j] = __builtin_amdgcn_mfma_f32_16x16x32_f16(af[i], bfv[j], acc[i][j], 0, 0, 0);
    }
    __syncthreads();
  }
  // here: all waves past the final barrier; staging LDS is dead -> smf may alias it

  if (EPI == EP_TANH) {                  // linv[col] = 1 / sum_k psum[k][col]
    if (tid < BN) {
      int col = nBase + tid;
      float ssum = 0.f;
      if (col < N)
        for (int k = 0; k < pnchunks; ++k) ssum += aux2[(size_t)k * N + col];
      smf[tid] = 1.f / ssum;
    }
    __syncthreads();
  }

  // epilogue: D row=(lane>>4)*4+r, col=lane&15 (m89-verified mapping)
  const int rBase = (lane >> 4) << 2;
  float lmax[FN];
  #pragma unroll
  for (int j = 0; j < FN; ++j) lmax[j] = -1e30f;
  #pragma unroll
  for (int i = 0; i < FM; ++i) {
    #pragma unroll
    for (int j = 0; j < FN; ++j) {
      #pragma unroll
      for (int r = 0; r < 4; ++r) {
        int row = mBase + wm * WTM + i * 16 + rBase + r;
        int col = nBase + wn * WTN + j * 16 + lr;
        if (row < M && col < N) {
          float v = acc[i][j][r];
          size_t o = (size_t)row * N + col;
          if (EPI == EP_LOGIT) {
            v = 0.5f * v - 0.25f * aux1[row];
            ((_Float16*)Cout)[o] = (_Float16)v;
            lmax[j] = fmaxf(lmax[j], v);
          } else if (EPI == EP_TANH) {
            v = tanhf(v + aux1[row]) * smf[col - nBase];
            ((_Float16*)Cout)[o] = (_Float16)v;
          } else if (EPI == EP_TANHP) {
            v = tanhf(v + aux1[row]);
            ((_Float16*)Cout)[o] = (_Float16)v;
          } else if (EPI == EP_F16) {
            ((_Float16*)Cout)[o] = (_Float16)v;
          } else if (EPI == EP_PART) {
            ((_Float16*)Cout)[(size_t)blockIdx.z * M * N + o] = (_Float16)v;
          } else {
            ((float*)Cout)[o] = v;
          }
        }
      }
    }
  }
  if (EPI == EP_LOGIT) {
    #pragma unroll
    for (int j = 0; j < FN; ++j) {
      float m = lmax[j];
      m = fmaxf(m, __shfl_xor(m, 16, 64));
      m = fmaxf(m, __shfl_xor(m, 32, 64));
      if ((lane >> 4) == 0) smf[wm * BN + wn * WTN + j * 16 + lr] = m;
    }
    __syncthreads();
    if (tid < BN) {
      int col = nBase + tid;
      if (col < N)
        pmax[(size_t)blockIdx.x * N + col] = fmaxf(smf[tid], smf[BN + tid]);
    }
  }
}

// ------------- fused logit + full column softmax (ncur fits in one block: BM == M) -------------
// Writes E'[j][col] = exp(logit - m_col) / l_col  (1/l folded in — no linv downstream).
template<int BM, int BN>
__launch_bounds__(256, 2)
__global__ void fused_ls(const _Float16* __restrict__ A,   // centers [M x K]
                         const _Float16* __restrict__ B,   // h_prev  [N x K]
                         _Float16* __restrict__ Eout,      // [M x N]
                         const float* __restrict__ cn,
                         int M, int N, int K) {
  constexpr int BK = 64;
  constexpr int WTM = BM / 2, WTN = BN / 2;
  constexpr int FM = WTM / 16, FN = WTN / 16;
  constexpr int TLD = BN + 4;                       // padded tile LD (bank stagger)
  constexpr int STAGE_B = (BM + BN) * BK * 2;
  constexpr int TILE_B  = BM * TLD * 4;
  constexpr int SM_B = STAGE_B > TILE_B ? STAGE_B : TILE_B;
  __shared__ __align__(16) char smem[SM_B];
  _Float16* As = (_Float16*)smem;
  _Float16* Bs = As + BM * BK;
  float* tile = (float*)smem;                       // reused after K-loop
  __shared__ float redm[256], reds[256];
  const int tid  = threadIdx.x;
  const int lane = tid & 63;
  const int wave = tid >> 6;
  const int wm = wave >> 1, wn = wave & 1;
  const int nBase = blockIdx.x * BN;
  const int lr    = lane & 15;
  const int kHalf = (lane >> 4) << 3;
  const int srOff  = lane >> 3;
  const int schunk = (lane & 7) ^ srOff;
  floatx4 acc[FM][FN] = {};
  constexpr int AV = BM * BK / (256 * 8);
  constexpr int BV = BN * BK / (256 * 8);

  for (int k0 = 0; k0 < K; k0 += BK) {
    #pragma unroll
    for (int v = 0; v < AV; ++v) {
      int rowBase = v * 32 + wave * 8;
      GLOAD_LDS16(A + (size_t)(rowBase + srOff) * K + k0 + schunk * 8, &As[rowBase * BK]);
    }
    #pragma unroll
    for (int v = 0; v < BV; ++v) {
      int rowBase = v * 32 + wave * 8;
      GLOAD_LDS16(B + (size_t)(nBase + rowBase + srOff) * K + k0 + schunk * 8, &Bs[rowBase * BK]);
    }
    __syncthreads();
    #pragma unroll
    for (int kk = 0; kk < BK; kk += 32) {
      const int q = (kk + kHalf) >> 3;
      half8 af[FM], bfv[FN];
      #pragma unroll
      for (int i = 0; i < FM; ++i) {
        int r = wm * WTM + i * 16 + lr;
        af[i] = *(const half8*)(&As[r * BK + ((q ^ (r & 7)) << 3)]);
      }
      #pragma unroll
      for (int j = 0; j < FN; ++j) {
        int r = wn * WTN + j * 16 + lr;
        bfv[j] = *(const half8*)(&Bs[r * BK + ((q ^ (r & 7)) << 3)]);
      }
      #pragma unroll
      for (int i = 0; i < FM; ++i)
        #pragma unroll
        for (int j = 0; j < FN; ++j)
          acc[i][j] = __builtin_amdgcn_mfma_f32_16x16x32_f16(af[i], bfv[j], acc[i][j], 0, 0, 0);
    }
    __syncthreads();                                // also protects staging->tile reuse
  }

  // logits -> fp32 LDS tile
  const int rBase = (lane >> 4) << 2;
  #pragma unroll
  for (int i = 0; i < FM; ++i)
    #pragma unroll
    for (int j = 0; j < FN; ++j)
      #pragma unroll
      for (int r = 0; r < 4; ++r) {
        int row = wm * WTM + i * 16 + rBase + r;    // row < BM == M
        int col = wn * WTN + j * 16 + lr;
        tile[row * TLD + col] = 0.5f * acc[i][j][r] - 0.25f * cn[row];
      }
  __syncthreads();

  // per-column softmax: P threads per column, rows strided
  constexpr int P = 256 / BN;
  const int c = tid & (BN - 1);
  const int p = tid / BN;
  float m = -1e30f;
  for (int j = p; j < M; j += P) m = fmaxf(m, tile[j * TLD + c]);
  redm[p * BN + c] = m;
  __syncthreads();
  float mf = redm[c];
  #pragma unroll
  for (int q = 1; q < P; ++q) mf = fmaxf(mf, redm[q * BN + c]);
  float s = 0.f;
  for (int j = p; j < M; j += P) {
    float e = __expf(tile[j * TLD + c] - mf);
    tile[j * TLD + c] = e;                          // own cells only
    s += e;
  }
  reds[p * BN + c] = s;
  __syncthreads();
  float l = 0.f;
  #pragma unroll
  for (int q = 0; q < P; ++q) l += reds[q * BN + c];
  const float li = 1.f / l;
  for (int j = p; j < M; j += P)
    Eout[(size_t)j * N + nBase + c] = (_Float16)(tile[j * TLD + c] * li);
}

// returns the BM actually used (host needs it for pmax chunk count)
template<int EPI>
static int launch_gemm(int M, int N, int K, const _Float16* A, const _Float16* B,
                       void* C, const float* a1, const float* a2, float* pmax,
                       int pnchunks, hipStream_t s) {
  long b128   = (long)cdiv(M, 128) * cdiv(N, 128);
  long b12864 = (long)cdiv(M, 128) * cdiv(N, 64);
  if (b128 >= 192) {
    gemm_nt<128, 128, EPI><<<dim3(cdiv(M, 128), cdiv(N, 128)), 256, 0, s>>>(
        A, B, C, a1, a2, pmax, pnchunks, M, N, K, K);
    return 128;
  } else if (M >= 128 && b12864 >= 192) {
    gemm_nt<128, 64, EPI><<<dim3(cdiv(M, 128), cdiv(N, 64)), 256, 0, s>>>(
        A, B, C, a1, a2, pmax, pnchunks, M, N, K, K);
    return 128;
  } else {
    gemm_nt<64, 64, EPI><<<dim3(cdiv(M, 64), cdiv(N, 64)), 256, 0, s>>>(
        A, B, C, a1, a2, pmax, pnchunks, M, N, K, K);
    return 64;
  }
}

static void launch_gemm_splitk(int M, int N, int K, int S,
                               const _Float16* A, const _Float16* B,
                               _Float16* Cpart, _Float16* Cout, hipStream_t s) {
  int kLen = K / S;
  long b128 = (long)cdiv(M, 128) * cdiv(N, 128) * S;
  if (M >= 128 && N >= 128 && b128 >= 256) {
    gemm_nt<128, 128, EP_PART><<<dim3(cdiv(M, 128), cdiv(N, 128), S), 256, 0, s>>>(
        A, B, Cpart, nullptr, nullptr, nullptr, 0, M, N, K, kLen);
  } else {
    gemm_nt<64, 64, EP_PART><<<dim3(cdiv(M, 64), cdiv(N, 64), S), 256, 0, s>>>(
        A, B, Cpart, nullptr, nullptr, nullptr, 0, M, N, K, kLen);
  }
  int mn = M * N;
  reduce_parts<<<cdiv(mn, 1024), 256, 0, s>>>(Cpart, Cout, mn, S);
}

extern "C" void kernel_launch(void* const* d_in, const int* in_sizes, int n_in,
                              void* d_out, int out_size, void* d_ws, size_t ws_size,
                              hipStream_t stream) {
  const float* h0 = (const float*)d_in[0];
  const float* c1 = (const float*)d_in[1];
  const float* c2 = (const float*)d_in[2];
  const float* c3 = (const float*)d_in[3];
  const float* W1 = (const float*)d_in[4];
  const float* b1 = (const float*)d_in[5];
  const float* W2 = (const float*)d_in[6];
  const float* b2 = (const float*)d_in[7];
  const float* W3 = (const float*)d_in[8];
  const float* b3 = (const float*)d_in[9];

  const int d = 1024;
  const int N0 = 16384, N1 = 2048, N2 = 256, N3 = 32;

  char* w = (char*)d_ws;
  size_t off = 0;
  auto alloc = [&](size_t bytes) {
    void* p = w + off;
    off += (bytes + 255) & ~(size_t)255;
    return p;
  };
  _Float16* hb  = (_Float16*)alloc((size_t)N0 * d * 2);   // 32 MB
  _Float16* cb1 = (_Float16*)alloc((size_t)N1 * d * 2);
  _Float16* cb2 = (_Float16*)alloc((size_t)N2 * d * 2);
  _Float16* cb3 = (_Float16*)alloc((size_t)N3 * d * 2);
  float* cn1 = (float*)alloc((size_t)N1 * 4);
  float* cn2 = (float*)alloc((size_t)N2 * 4);
  float* cn3 = (float*)alloc((size_t)N3 * 4);
  _Float16* Wb1 = (_Float16*)alloc((size_t)d * d * 2);
  _Float16* Wb2 = (_Float16*)alloc((size_t)d * d * 2);
  _Float16* Wb3 = (_Float16*)alloc((size_t)d * d * 2);
  _Float16* ST = (_Float16*)alloc((size_t)N1 * N0 * 2);   // 64 MB, E overwrites in place
  _Float16* tT = (_Float16*)alloc((size_t)d * N0 * 2);    // 32 MB
  float* pmax = (float*)alloc((size_t)32 * N0 * 4);       // per-block column maxes (L1)
  float* psum = (float*)alloc((size_t)32 * N0 * 4);       // per-chunk column sums (L1)
  _Float16* h1b = (_Float16*)alloc((size_t)N1 * d * 2);
  _Float16* h2b = (_Float16*)alloc((size_t)N2 * d * 2);
  _Float16* Cpart = (_Float16*)alloc((size_t)8 * N1 * d * 2);  // 32 MB fp16 split-K partials
  _Float16* E = ST;
  (void)ws_size; (void)in_sizes; (void)n_in; (void)out_size;

  // ---- prep: one kernel (casts + center norms) ----
  int nh = N0 * d, nw = d * d;
  int castBlocks = cdiv(nh + 3 * nw, 1024);
  prep<<<castBlocks + N1 + N2 + N3, 256, 0, stream>>>(
      h0, W1, W2, W3, c1, c2, c3, hb, Wb1, Wb2, Wb3, cb1, cb2, cb3,
      cn1, cn2, cn3, nh, nw, castBlocks, N1, N2);

  // ---- level 1: h[16384] -> h1[2048] (2-pass softmax; ncur too big for in-block) ----
  int bm = launch_gemm<EP_LOGIT>(N1, N0, d, cb1, hb, ST, cn1, nullptr, pmax, 0, stream);
  colexp_partial<<<dim3(N0 / 1024, cdiv(N1, SM_CHUNK)), 256, 0, stream>>>(
      ST, pmax, psum, cdiv(N1, bm), N1, N0);
  launch_gemm<EP_TANH>(d, N0, d, Wb1, hb, tT, b1, psum, nullptr, cdiv(N1, SM_CHUNK), stream);
  launch_gemm_splitk(N1, d, N0, 8, E, tT, Cpart, h1b, stream);   // 16x8x8 = 1024 blocks

  // ---- level 2: h1[2048] -> h2[256] (in-block softmax, 1/l folded into E') ----
  fused_ls<256, 64><<<N1 / 64, 256, 0, stream>>>(cb2, h1b, E, cn2, N2, N1, d);
  launch_gemm<EP_TANHP>(d, N1, d, Wb2, h1b, tT, b2, nullptr, nullptr, 0, stream);
  launch_gemm_splitk(N2, d, N1, 8, E, tT, Cpart, h2b, stream);   // 64x64: 4x16x8 = 512 blocks

  // ---- level 3: h2[256] -> out[32][1024] fp32 ----
  fused_ls<32, 64><<<N2 / 64, 256, 0, stream>>>(cb3, h2b, E, cn3, N3, N2, d);
  launch_gemm<EP_TANHP>(d, N2, d, Wb3, h2b, tT, b3, nullptr, nullptr, 0, stream);
  launch_gemm<EP_F32>(N3, d, N2, E, tT, d_out, nullptr, nullptr, nullptr, 0, stream);
}